// Round 1
// baseline (91.817 us; speedup 1.0000x reference)
//
#include <hip/hip_runtime.h>

// LocalInstanceNorm collapses analytically to a per-pixel channel norm:
//   out[b,c,y,x] = (x[b,c,y,x] - mean_c) / (std_c(ddof=1) + 1e-5)
// because mean/std over channels depend only on the absolute pixel, and the
// gaussian-weighted fold divided by the gaussian fold cancels exactly
// (every pixel is covered by >=1 window; identical window sums in num/denom).

constexpr int B = 4;
constexpr int C = 64;
constexpr int H = 384;
constexpr int W = 384;
constexpr int HW = H * W;
constexpr float EPS = 1e-5f;

__global__ __launch_bounds__(256) void local_instance_norm_kernel(
    const float* __restrict__ x, float* __restrict__ out) {
    int pix = blockIdx.x * blockDim.x + threadIdx.x;  // 0 .. B*HW-1
    if (pix >= B * HW) return;
    int b = pix / HW;
    int s = pix - b * HW;

    const float* xp = x + (size_t)b * C * HW + s;
    float* op = out + (size_t)b * C * HW + s;

    float v[C];
    float sum = 0.f;
#pragma unroll
    for (int c = 0; c < C; ++c) {
        float t = xp[(size_t)c * HW];
        v[c] = t;
        sum += t;
    }
    float mean = sum * (1.0f / C);

    float ss = 0.f;
#pragma unroll
    for (int c = 0; c < C; ++c) {
        float d = v[c] - mean;
        ss += d * d;
    }
    float var = ss * (1.0f / (C - 1));  // unbiased (ddof=1)
    float inv = 1.0f / (sqrtf(var) + EPS);

#pragma unroll
    for (int c = 0; c < C; ++c) {
        op[(size_t)c * HW] = (v[c] - mean) * inv;
    }
}

extern "C" void kernel_launch(void* const* d_in, const int* in_sizes, int n_in,
                              void* d_out, int out_size, void* d_ws, size_t ws_size,
                              hipStream_t stream) {
    const float* x = (const float*)d_in[0];
    float* out = (float*)d_out;

    int total = B * HW;            // one thread per (b, y, x) pixel
    int block = 256;
    int grid = (total + block - 1) / block;  // 2304 blocks
    local_instance_norm_kernel<<<grid, block, 0, stream>>>(x, out);
}

// Round 2
// 56.719 us; speedup vs baseline: 1.6188x; 1.6188x over previous
//
#include <hip/hip_runtime.h>

// out[b,c,y,x] = (x[b,c,y,x] - mean_c) / (std_c(ddof=1) + 1e-5)
// (the gaussian unfold/fold cancels exactly; see round-0 derivation).
//
// Round-1 lesson: per-thread v[64] got rematerialized (VGPR=36 -> x read ~3x).
// Fix: LDS-stage each 256-pixel x 64-channel tile once with float4 loads;
// re-read LDS (cheap) for the three passes instead of global.

constexpr int B = 4;
constexpr int C = 64;
constexpr int H = 384;
constexpr int W = 384;
constexpr int HW = H * W;          // 147456, divisible by 256
constexpr int PIX_PER_BLK = 256;   // pixels per block
constexpr float EPS = 1e-5f;

__global__ __launch_bounds__(256) void local_instance_norm_kernel(
    const float* __restrict__ x, float* __restrict__ out) {
    __shared__ float lds[C * PIX_PER_BLK];  // 64 KB: [c][p], p = pixel in tile

    const int t = threadIdx.x;                     // 0..255
    const int tile = blockIdx.x;                   // 0..2303
    const int b = tile / (HW / PIX_PER_BLK);       // 576 tiles per batch
    const int s_base = (tile % (HW / PIX_PER_BLK)) * PIX_PER_BLK;

    const float* xp = x + (size_t)b * C * HW + s_base;
    float* op = out + (size_t)b * C * HW + s_base;

    // Stage: 4096 float4s, 16 per thread. Wave w at iter j loads channel
    // c = j*4 + w contiguously (64 float4 = 1 KB per wave per instr).
#pragma unroll
    for (int j = 0; j < 16; ++j) {
        int idx = j * 256 + t;        // 0..4095
        int c = idx >> 6;             // idx / 64
        int p4 = idx & 63;            // float4 index within 256 pixels
        float4 val = *reinterpret_cast<const float4*>(xp + (size_t)c * HW + p4 * 4);
        *reinterpret_cast<float4*>(&lds[c * PIX_PER_BLK + p4 * 4]) = val;
    }
    __syncthreads();

    // Thread t owns pixel t. lds[c*256+t]: lanes -> distinct banks (2-way, free).
    float sum = 0.f;
#pragma unroll
    for (int c = 0; c < C; ++c) sum += lds[c * PIX_PER_BLK + t];
    float mean = sum * (1.0f / C);

    float ss = 0.f;
#pragma unroll
    for (int c = 0; c < C; ++c) {
        float d = lds[c * PIX_PER_BLK + t] - mean;
        ss += d * d;
    }
    float var = ss * (1.0f / (C - 1));     // unbiased (ddof=1)
    float inv = 1.0f / (sqrtf(var) + EPS);

#pragma unroll
    for (int c = 0; c < C; ++c) {
        op[(size_t)c * HW + t] = (lds[c * PIX_PER_BLK + t] - mean) * inv;
    }
}

extern "C" void kernel_launch(void* const* d_in, const int* in_sizes, int n_in,
                              void* d_out, int out_size, void* d_ws, size_t ws_size,
                              hipStream_t stream) {
    const float* x = (const float*)d_in[0];
    float* out = (float*)d_out;

    int grid = (B * HW) / PIX_PER_BLK;  // 2304 blocks
    local_instance_norm_kernel<<<grid, 256, 0, stream>>>(x, out);
}

// Round 3
// 56.230 us; speedup vs baseline: 1.6329x; 1.0087x over previous
//
#include <hip/hip_runtime.h>

// out[b,c,y,x] = (x[b,c,y,x] - mean_c) / (std_c(ddof=1) + 1e-5)
// (gaussian unfold/fold cancels exactly; round-0 derivation).
//
// Round-2 lesson: loads were float4 but stores were scalar dword (256 B/wave).
// Fix: normalize in-place in LDS, then mirror the staging pattern for the
// write-out -> 16 float4 stores/thread (1 KB/wave/instr) on the store side too.

constexpr int B = 4;
constexpr int C = 64;
constexpr int H = 384;
constexpr int W = 384;
constexpr int HW = H * W;          // 147456, divisible by 256
constexpr int PIX_PER_BLK = 256;
constexpr float EPS = 1e-5f;

__global__ __launch_bounds__(256) void local_instance_norm_kernel(
    const float* __restrict__ x, float* __restrict__ out) {
    __shared__ float lds[C * PIX_PER_BLK];  // 64 KB: [c][p]

    const int t = threadIdx.x;                   // 0..255
    const int tile = blockIdx.x;                 // 0..2303
    const int b = tile / (HW / PIX_PER_BLK);
    const int s_base = (tile % (HW / PIX_PER_BLK)) * PIX_PER_BLK;

    const float* xp = x + (size_t)b * C * HW + s_base;
    float* op = out + (size_t)b * C * HW + s_base;

    // Stage in: 4096 float4s, 16 per thread, contiguous per channel.
#pragma unroll
    for (int j = 0; j < 16; ++j) {
        int idx = j * 256 + t;    // 0..4095
        int c = idx >> 6;
        int p4 = idx & 63;
        float4 val = *reinterpret_cast<const float4*>(xp + (size_t)c * HW + p4 * 4);
        *reinterpret_cast<float4*>(&lds[c * PIX_PER_BLK + p4 * 4]) = val;
    }
    __syncthreads();

    // Thread t owns pixel t; lds[c*256+t] -> 2-way bank aliasing (free).
    float sum = 0.f;
#pragma unroll
    for (int c = 0; c < C; ++c) sum += lds[c * PIX_PER_BLK + t];
    float mean = sum * (1.0f / C);

    float ss = 0.f;
#pragma unroll
    for (int c = 0; c < C; ++c) {
        float d = lds[c * PIX_PER_BLK + t] - mean;
        ss += d * d;
    }
    float var = ss * (1.0f / (C - 1));   // unbiased (ddof=1)
    float inv = 1.0f / (sqrtf(var) + EPS);

    // Normalize in place.
#pragma unroll
    for (int c = 0; c < C; ++c) {
        float d = lds[c * PIX_PER_BLK + t] - mean;
        lds[c * PIX_PER_BLK + t] = d * inv;
    }
    __syncthreads();

    // Stage out: mirror of the load pattern -> float4 stores.
#pragma unroll
    for (int j = 0; j < 16; ++j) {
        int idx = j * 256 + t;
        int c = idx >> 6;
        int p4 = idx & 63;
        float4 val = *reinterpret_cast<const float4*>(&lds[c * PIX_PER_BLK + p4 * 4]);
        *reinterpret_cast<float4*>(op + (size_t)c * HW + p4 * 4) = val;
    }
}

extern "C" void kernel_launch(void* const* d_in, const int* in_sizes, int n_in,
                              void* d_out, int out_size, void* d_ws, size_t ws_size,
                              hipStream_t stream) {
    const float* x = (const float*)d_in[0];
    float* out = (float*)d_out;

    int grid = (B * HW) / PIX_PER_BLK;  // 2304 blocks
    local_instance_norm_kernel<<<grid, 256, 0, stream>>>(x, out);
}

// Round 4
// 55.942 us; speedup vs baseline: 1.6413x; 1.0052x over previous
//
#include <hip/hip_runtime.h>

// out[b,c,y,x] = (x[b,c,y,x] - mean_c) / (std_c(ddof=1) + 1e-5)
// (gaussian unfold/fold cancels exactly; round-0 derivation).
//
// Round-3 lesson: 64KB data-LDS -> 2 blocks/CU and 384KB LDS traffic behind
// 3 barriers. Fix: keep each thread's 16 float4s in REGISTERS (fixed pixel
// quad per thread), one-pass sum/sumsq during load, exchange only 8KB of
// per-wave partial stats through LDS (single barrier), normalize from regs.

constexpr int B = 4;
constexpr int C = 64;
constexpr int H = 384;
constexpr int W = 384;
constexpr int HW = H * W;          // 147456, divisible by 256
constexpr int PIX_PER_BLK = 256;   // 64 pixel-quads, one per lane
constexpr float EPS = 1e-5f;

__global__ __launch_bounds__(256, 2) void local_instance_norm_kernel(
    const float* __restrict__ x, float* __restrict__ out) {
    __shared__ float4 ssum[4][64];   // [wave][lane] partial sums   (4 KB)
    __shared__ float4 sssq[4][64];   // [wave][lane] partial sumsqs (4 KB)

    const int t = threadIdx.x;
    const int w = t >> 6;            // wave 0..3
    const int l = t & 63;            // lane 0..63
    const int tile = blockIdx.x;     // 0..2303
    const int b = tile / (HW / PIX_PER_BLK);
    const int s_base = (tile % (HW / PIX_PER_BLK)) * PIX_PER_BLK;

    const float* xp = x + (size_t)b * C * HW + s_base + 4 * l;
    float* op = out + (size_t)b * C * HW + s_base + 4 * l;

    // Load: thread (w,l) owns pixels 4l..4l+3, channels c = 4j+w.
    // Each wave instr: 64 lanes x 16B = 1KB contiguous. 16 loads in flight.
    float4 v[16];
#pragma unroll
    for (int j = 0; j < 16; ++j) {
        v[j] = *reinterpret_cast<const float4*>(xp + (size_t)(4 * j + w) * HW);
    }

    float4 sum = make_float4(0.f, 0.f, 0.f, 0.f);
    float4 ssq = make_float4(0.f, 0.f, 0.f, 0.f);
#pragma unroll
    for (int j = 0; j < 16; ++j) {
        sum.x += v[j].x; sum.y += v[j].y; sum.z += v[j].z; sum.w += v[j].w;
        ssq.x += v[j].x * v[j].x; ssq.y += v[j].y * v[j].y;
        ssq.z += v[j].z * v[j].z; ssq.w += v[j].w * v[j].w;
    }
    ssum[w][l] = sum;
    sssq[w][l] = ssq;
    __syncthreads();

    // Combine the 4 waves' partials for this lane's pixel quad.
    float4 S = make_float4(0.f, 0.f, 0.f, 0.f);
    float4 Q = make_float4(0.f, 0.f, 0.f, 0.f);
#pragma unroll
    for (int ww = 0; ww < 4; ++ww) {
        float4 a = ssum[ww][l];
        float4 q = sssq[ww][l];
        S.x += a.x; S.y += a.y; S.z += a.z; S.w += a.w;
        Q.x += q.x; Q.y += q.y; Q.z += q.z; Q.w += q.w;
    }

    float4 mean, inv;
    {
        const float rn = 1.0f / C;
        const float rn1 = 1.0f / (C - 1);
        mean.x = S.x * rn; mean.y = S.y * rn; mean.z = S.z * rn; mean.w = S.w * rn;
        float vx = fmaxf((Q.x - (float)C * mean.x * mean.x) * rn1, 0.f);
        float vy = fmaxf((Q.y - (float)C * mean.y * mean.y) * rn1, 0.f);
        float vz = fmaxf((Q.z - (float)C * mean.z * mean.z) * rn1, 0.f);
        float vw = fmaxf((Q.w - (float)C * mean.w * mean.w) * rn1, 0.f);
        inv.x = 1.0f / (sqrtf(vx) + EPS);
        inv.y = 1.0f / (sqrtf(vy) + EPS);
        inv.z = 1.0f / (sqrtf(vz) + EPS);
        inv.w = 1.0f / (sqrtf(vw) + EPS);
    }

    // Normalize from registers, float4 stores (1KB/wave/instr).
#pragma unroll
    for (int j = 0; j < 16; ++j) {
        float4 o;
        o.x = (v[j].x - mean.x) * inv.x;
        o.y = (v[j].y - mean.y) * inv.y;
        o.z = (v[j].z - mean.z) * inv.z;
        o.w = (v[j].w - mean.w) * inv.w;
        *reinterpret_cast<float4*>(op + (size_t)(4 * j + w) * HW) = o;
    }
}

extern "C" void kernel_launch(void* const* d_in, const int* in_sizes, int n_in,
                              void* d_out, int out_size, void* d_ws, size_t ws_size,
                              hipStream_t stream) {
    const float* x = (const float*)d_in[0];
    float* out = (float*)d_out;

    int grid = (B * HW) / PIX_PER_BLK;  // 2304 blocks
    local_instance_norm_kernel<<<grid, 256, 0, stream>>>(x, out);
}

// Round 5
// 48.609 us; speedup vs baseline: 1.8889x; 1.1508x over previous
//
#include <hip/hip_runtime.h>

// out[b,c,y,x] = (x[b,c,y,x] - mean_c) / (std_c(ddof=1) + 1e-5)
// (gaussian unfold/fold cancels exactly; round-0 derivation).
//
// Round-4 lesson: 56us plateau across 3 structures. Steady-state FETCH=74MB
// shows output writes evict the input from the 256MB L3 (151+151 > 256).
// Fix: non-temporal (nt) stores for the write-once output -> input stays
// L3-resident across replays, HBM carries only the write stream.

constexpr int B = 4;
constexpr int C = 64;
constexpr int H = 384;
constexpr int W = 384;
constexpr int HW = H * W;          // 147456, divisible by 256
constexpr int PIX_PER_BLK = 256;   // 64 pixel-quads, one per lane
constexpr float EPS = 1e-5f;

typedef float f4 __attribute__((ext_vector_type(4)));  // native vector type
                                                       // (HIP float4 is a
                                                       // struct; the
                                                       // nontemporal builtin
                                                       // needs a real vector)

__global__ __launch_bounds__(256, 2) void local_instance_norm_kernel(
    const float* __restrict__ x, float* __restrict__ out) {
    __shared__ f4 ssum[4][64];   // [wave][lane] partial sums   (4 KB)
    __shared__ f4 sssq[4][64];   // [wave][lane] partial sumsqs (4 KB)

    const int t = threadIdx.x;
    const int w = t >> 6;            // wave 0..3
    const int l = t & 63;            // lane 0..63
    const int tile = blockIdx.x;     // 0..2303
    const int b = tile / (HW / PIX_PER_BLK);
    const int s_base = (tile % (HW / PIX_PER_BLK)) * PIX_PER_BLK;

    const float* xp = x + (size_t)b * C * HW + s_base + 4 * l;
    float* op = out + (size_t)b * C * HW + s_base + 4 * l;

    // Load: thread (w,l) owns pixels 4l..4l+3, channels c = 4j+w.
    // Each wave instr: 64 lanes x 16B = 1KB contiguous.
    f4 v[16];
#pragma unroll
    for (int j = 0; j < 16; ++j) {
        v[j] = *reinterpret_cast<const f4*>(xp + (size_t)(4 * j + w) * HW);
    }

    f4 sum = (f4)(0.f);
    f4 ssq = (f4)(0.f);
#pragma unroll
    for (int j = 0; j < 16; ++j) {
        sum += v[j];
        ssq += v[j] * v[j];
    }
    ssum[w][l] = sum;
    sssq[w][l] = ssq;
    __syncthreads();

    // Combine the 4 waves' partials for this lane's pixel quad.
    f4 S = (f4)(0.f);
    f4 Q = (f4)(0.f);
#pragma unroll
    for (int ww = 0; ww < 4; ++ww) {
        S += ssum[ww][l];
        Q += sssq[ww][l];
    }

    const float rn = 1.0f / C;
    const float rn1 = 1.0f / (C - 1);
    f4 mean = S * rn;
    f4 var = (Q - (float)C * mean * mean) * rn1;
    f4 inv;
    inv.x = 1.0f / (sqrtf(fmaxf(var.x, 0.f)) + EPS);
    inv.y = 1.0f / (sqrtf(fmaxf(var.y, 0.f)) + EPS);
    inv.z = 1.0f / (sqrtf(fmaxf(var.z, 0.f)) + EPS);
    inv.w = 1.0f / (sqrtf(fmaxf(var.w, 0.f)) + EPS);

    // Normalize from registers; nt float4 stores (no L2/L3 allocation).
#pragma unroll
    for (int j = 0; j < 16; ++j) {
        f4 o = (v[j] - mean) * inv;
        __builtin_nontemporal_store(o, reinterpret_cast<f4*>(op + (size_t)(4 * j + w) * HW));
    }
}

extern "C" void kernel_launch(void* const* d_in, const int* in_sizes, int n_in,
                              void* d_out, int out_size, void* d_ws, size_t ws_size,
                              hipStream_t stream) {
    const float* x = (const float*)d_in[0];
    float* out = (float*)d_out;

    int grid = (B * HW) / PIX_PER_BLK;  // 2304 blocks
    local_instance_norm_kernel<<<grid, 256, 0, stream>>>(x, out);
}